// Round 13
// baseline (171.951 us; speedup 1.0000x reference)
//
#include <hip/hip_runtime.h>

// CIN forward: B=2048, F=32, DIM=64, layers (128,128)
// out[b, 0:64]   = sum_d relu(W0 @ z0 + b0)[64:128, d]
// out[b, 64:192] = sum_d relu(W1 @ z1 + b1)[0:128, d]
// z0[h*32+m, d] = x[h,d]*x[m,d]   (h,m in [0,32))
// z1[h*32+m, d] = h1[h,d]*x[m,d]  (h in [0,64), m in [0,32)), h1 = layer0 rows 0..63
//
// R13: halve bfr-formation VALU for layer 1 (2/3 of work) by doubling the
// bfr sharing factor: wave (p, rh) owns ALL 128 rows x 32 d-cols (t=rh*2,
// rh*2+1). Per K-step: 2 bfr (8 pk_mul) feed 16 MFMAs -> 0.5 pk_mul/MFMA.
// Precedent: R0->R4 (2 -> 1 pk_mul/MFMA) was the only change that ever moved
// both the VALU ratio AND time (96->87us). acc stays 64 AGPR (8x2 v4f);
// A-frags half-step ping-pong (8 v8h live; compiler-tracked loads — R11
// showed manual vmcnt + forced regs is fatal); W1 L2 traffic x2 (R6: traffic
// not binding). d-sum now spans rh waves -> 2KB LDS partials + 1 sync.
// L0 unchanged (R5c form); setprio dropped (R12: neutral).
//
// A-frag swizzle (16x16x32): wsw[ks*4096 + s*512 + lane*8 + j]
//   = W[(s*16 + (lane&15))*K + ks*32 + (lane>>4)*8 + j]

#define BATCH 2048
#define FSZ   32
#define DIM   64
#define K0    1024
#define K1    2048
#define OUTC  192

#define W0_ELEMS (128 * K0)            // 131072 f16
#define W1_ELEMS (128 * K1)            // 262144 f16
#define TOT_ELEMS (W0_ELEMS + W1_ELEMS)
#define CVT_THREADS (TOT_ELEMS / 4)    // 98304 -> 384 blocks

typedef _Float16 v8h __attribute__((ext_vector_type(8)));
typedef _Float16 v4h __attribute__((ext_vector_type(4)));
typedef _Float16 v2h __attribute__((ext_vector_type(2)));
typedef float    v4f __attribute__((ext_vector_type(4)));

#define XT_PITCH 40   // xT[d][m]: 80B rows, 16B-aligned v8h loads

// One thread per 4 output f16: coalesced 8B stores, aligned float4 reads.
__global__ void convert_w_kernel(const float* __restrict__ W0,
                                 const float* __restrict__ W1,
                                 _Float16* __restrict__ wsw) {
    int t = blockIdx.x * blockDim.x + threadIdx.x;
    if (t >= CVT_THREADS) return;
    int e = t * 4;
    const float* src;
    _Float16* dst;
    if (e < W0_ELEMS) {
        int j0 = e & 7, lane = (e >> 3) & 63, s = (e >> 9) & 7, ks = e >> 12;
        src = W0 + (size_t)(s * 16 + (lane & 15)) * K0
                 + ks * 32 + (lane >> 4) * 8 + j0;
        dst = wsw + e;
    } else {
        int u = e - W0_ELEMS;
        int j0 = u & 7, lane = (u >> 3) & 63, s = (u >> 9) & 7, ks = u >> 12;
        src = W1 + (size_t)(s * 16 + (lane & 15)) * K1
                 + ks * 32 + (lane >> 4) * 8 + j0;
        dst = wsw + W0_ELEMS + u;
    }
    float4 v = *(const float4*)src;
    dst[0] = (_Float16)v.x;
    dst[1] = (_Float16)v.y;
    dst[2] = (_Float16)v.z;
    dst[3] = (_Float16)v.w;
}

__device__ __forceinline__ v4f mfma16(v8h a, v8h b, v4f c) {
    return __builtin_amdgcn_mfma_f32_16x16x32_f16(a, b, c, 0, 0, 0);
}

__global__ __launch_bounds__(256, 4) void cin_kernel(
    const float* __restrict__ X,      // (B, 32, 64) fp32
    const float* __restrict__ b0,     // (128,)
    const float* __restrict__ b1,     // (128,)
    const _Float16* __restrict__ Wsw, // swizzled W0 then W1 (f16)
    float* __restrict__ out)          // (B, 192) fp32
{
    __shared__ _Float16 xT[2][DIM * XT_PITCH];   // xT[p][d][m]      (10240 B)
    __shared__ _Float16 xS[2][FSZ * 64];         // xS[p][m][c*4+t]  ( 8192 B)
    __shared__ _Float16 h1S[2][64 * 64];         // h1S[p][h][c*4+t] (16384 B)
    __shared__ float    pbuf[2][2][128];         // L1 d-sum partials ( 2048 B)

    const int b0i  = blockIdx.x * 2;
    const int tid  = threadIdx.x;
    const int wave = tid >> 6;
    const int lane = tid & 63;
    const int p    = wave & 1;        // batch member
    const int rh   = wave >> 1;       // L0: row half; L1: d half
    const int quad = lane >> 4;
    const int col  = lane & 15;

    // ---- stage both batches' x -> LDS (both layouts, f16) ----
    #pragma unroll
    for (int i = 0; i < 4; ++i) {
        int idx = tid + i * 256;               // float4 index 0..1023
        int pp = idx >> 9, r4 = idx & 511;
        float4 v = *(const float4*)(X + (size_t)(b0i + pp) * (FSZ * DIM) + r4 * 4);
        int m = (r4 * 4) >> 6, d = (r4 * 4) & 63;
        int tq = d >> 4, cc = d & 15;          // constant within the float4
        _Float16 f0 = (_Float16)v.x, f1 = (_Float16)v.y,
                 f2 = (_Float16)v.z, f3 = (_Float16)v.w;
        xT[pp][(d + 0) * XT_PITCH + m] = f0;
        xT[pp][(d + 1) * XT_PITCH + m] = f1;
        xT[pp][(d + 2) * XT_PITCH + m] = f2;
        xT[pp][(d + 3) * XT_PITCH + m] = f3;
        xS[pp][m * 64 + (cc + 0) * 4 + tq] = f0;
        xS[pp][m * 64 + (cc + 1) * 4 + tq] = f1;
        xS[pp][m * 64 + (cc + 2) * 4 + tq] = f2;
        xS[pp][m * 64 + (cc + 3) * 4 + tq] = f3;
    }
    __syncthreads();

    // K-invariant x parts of B fragments: xv8[t][j] = x[quad*8+j][16t+col]
    v8h xv8[4];
    #pragma unroll
    for (int t = 0; t < 4; ++t)
        xv8[t] = *(const v8h*)(&xT[p][(16 * t + col) * XT_PITCH + quad * 8]);

    const _Float16* Wb   = Wsw + (size_t)(rh * 4) * 512 + (size_t)lane * 8;
    const _Float16* xSp  = &xS[p][col * 4];

    // ================= layer 0 (R5c form, unchanged) =================
    v4f acc[4][4];
    #pragma unroll
    for (int f = 0; f < 4; ++f)
        #pragma unroll
        for (int t = 0; t < 4; ++t) acc[f][t] = (v4f)0.0f;

    {
        v8h aC[4], aN[4];
        v4h svC, svN;
        #pragma unroll
        for (int i = 0; i < 4; ++i) aC[i] = *(const v8h*)(Wb + i * 512);
        svC = *(const v4h*)(xSp);
        #pragma unroll 2
        for (int ks = 0; ks < 32; ++ks) {
            const int kn = (ks + 1) & 31;      // clamped prefetch
            const _Float16* Wn = Wb + (size_t)kn * 4096;
            #pragma unroll
            for (int i = 0; i < 4; ++i) aN[i] = *(const v8h*)(Wn + i * 512);
            svN = *(const v4h*)(xSp + kn * 64);
            #pragma unroll
            for (int t = 0; t < 4; ++t) {
                _Float16 s = svC[t];
                v8h s8 = {s, s, s, s, s, s, s, s};
                v8h bfr = s8 * xv8[t];
                acc[0][t] = mfma16(aC[0], bfr, acc[0][t]);
                acc[1][t] = mfma16(aC[1], bfr, acc[1][t]);
                acc[2][t] = mfma16(aC[2], bfr, acc[2][t]);
                acc[3][t] = mfma16(aC[3], bfr, acc[3][t]);
            }
            #pragma unroll
            for (int i = 0; i < 4; ++i) aC[i] = aN[i];
            svC = svN;
        }
    }

    // ---- epilogue 0 ----
    // rh=0: rows 0..63 -> h1S[p] (packed v4h writes); rh=1: rows 64..127 -> out
    if (rh == 0) {
        #pragma unroll
        for (int f = 0; f < 4; ++f) {
            #pragma unroll
            for (int reg = 0; reg < 4; ++reg) {
                const int o = f * 16 + quad * 4 + reg;
                const float bias = b0[o];
                v4h pk;
                #pragma unroll
                for (int t = 0; t < 4; ++t) {
                    float v = acc[f][t][reg] + bias;
                    v = v > 0.0f ? v : 0.0f;
                    pk[t] = (_Float16)v;
                }
                *(v4h*)(&h1S[p][o * 64 + col * 4]) = pk;
            }
        }
    } else {
        #pragma unroll
        for (int f = 0; f < 4; ++f) {
            #pragma unroll
            for (int reg = 0; reg < 4; ++reg) {
                const int o = 64 + f * 16 + quad * 4 + reg;
                const float bias = b0[o];
                float s = 0.0f;
                #pragma unroll
                for (int t = 0; t < 4; ++t) {
                    float v = acc[f][t][reg] + bias;
                    s += (v > 0.0f ? v : 0.0f);
                }
                s += __shfl_xor(s, 1);
                s += __shfl_xor(s, 2);
                s += __shfl_xor(s, 4);
                s += __shfl_xor(s, 8);
                if (col == 0) out[(size_t)(b0i + p) * OUTC + (o - 64)] = s;
            }
        }
    }
    __syncthreads();   // h1S visible to all waves

    // ===== layer 1: 8 streams x 2 d-groups per wave (t = rh*2, rh*2+1) =====
    // This wave's K-invariant x parts (uniform select; no runtime indexing)
    v8h xw0 = (rh == 0) ? xv8[0] : xv8[2];
    v8h xw1 = (rh == 0) ? xv8[1] : xv8[3];

    v4f a1[8][2];
    #pragma unroll
    for (int f = 0; f < 8; ++f) {
        a1[f][0] = (v4f)0.0f;
        a1[f][1] = (v4f)0.0f;
    }

    {
        const _Float16* Wb1 = Wsw + W0_ELEMS + (size_t)lane * 8;
        const _Float16* hSp = &h1S[p][col * 4 + rh * 2];
        v8h G0, G1, G2, G3, H0, H1, H2, H3;
        v2h svC, svN;
        G0 = *(const v8h*)(Wb1);
        G1 = *(const v8h*)(Wb1 + 512);
        G2 = *(const v8h*)(Wb1 + 1024);
        G3 = *(const v8h*)(Wb1 + 1536);
        svC = *(const v2h*)(hSp);
        #pragma unroll 1
        for (int ks = 0; ks < 64; ++ks) {
            const int kn = (ks + 1) & 63;
            const _Float16* Wc = Wb1 + (size_t)ks * 4096;
            const _Float16* Wn = Wb1 + (size_t)kn * 4096;
            // phase A: load streams 4..7 of ks; compute f = 0..3 with G
            H0 = *(const v8h*)(Wc + 2048);
            H1 = *(const v8h*)(Wc + 2560);
            H2 = *(const v8h*)(Wc + 3072);
            H3 = *(const v8h*)(Wc + 3584);
            svN = *(const v2h*)(hSp + kn * 64);
            _Float16 s0 = svC[0], s1 = svC[1];
            v8h s08 = {s0, s0, s0, s0, s0, s0, s0, s0};
            v8h s18 = {s1, s1, s1, s1, s1, s1, s1, s1};
            v8h bf0 = s08 * xw0;
            v8h bf1 = s18 * xw1;
            a1[0][0] = mfma16(G0, bf0, a1[0][0]);
            a1[0][1] = mfma16(G0, bf1, a1[0][1]);
            a1[1][0] = mfma16(G1, bf0, a1[1][0]);
            a1[1][1] = mfma16(G1, bf1, a1[1][1]);
            a1[2][0] = mfma16(G2, bf0, a1[2][0]);
            a1[2][1] = mfma16(G2, bf1, a1[2][1]);
            a1[3][0] = mfma16(G3, bf0, a1[3][0]);
            a1[3][1] = mfma16(G3, bf1, a1[3][1]);
            // phase B: load streams 0..3 of ks+1; compute f = 4..7 with H
            G0 = *(const v8h*)(Wn);
            G1 = *(const v8h*)(Wn + 512);
            G2 = *(const v8h*)(Wn + 1024);
            G3 = *(const v8h*)(Wn + 1536);
            a1[4][0] = mfma16(H0, bf0, a1[4][0]);
            a1[4][1] = mfma16(H0, bf1, a1[4][1]);
            a1[5][0] = mfma16(H1, bf0, a1[5][0]);
            a1[5][1] = mfma16(H1, bf1, a1[5][1]);
            a1[6][0] = mfma16(H2, bf0, a1[6][0]);
            a1[6][1] = mfma16(H2, bf1, a1[6][1]);
            a1[7][0] = mfma16(H3, bf0, a1[7][0]);
            a1[7][1] = mfma16(H3, bf1, a1[7][1]);
            svC = svN;
        }
    }

    // ---- epilogue 1: per-wave 32-d partials -> pbuf, combine across rh ----
    #pragma unroll
    for (int f = 0; f < 8; ++f) {
        #pragma unroll
        for (int reg = 0; reg < 4; ++reg) {
            const int o = f * 16 + quad * 4 + reg;
            const float bias = b1[o];
            float v0 = a1[f][0][reg] + bias; v0 = v0 > 0.0f ? v0 : 0.0f;
            float v1 = a1[f][1][reg] + bias; v1 = v1 > 0.0f ? v1 : 0.0f;
            float s = v0 + v1;
            s += __shfl_xor(s, 1);
            s += __shfl_xor(s, 2);
            s += __shfl_xor(s, 4);
            s += __shfl_xor(s, 8);
            if (col == 0) pbuf[p][rh][o] = s;
        }
    }
    __syncthreads();
    if (rh == 0) {
        float* op = out + (size_t)(b0i + p) * OUTC + 64;
        op[lane]      = pbuf[p][0][lane]      + pbuf[p][1][lane];
        op[64 + lane] = pbuf[p][0][64 + lane] + pbuf[p][1][64 + lane];
    }
}

extern "C" void kernel_launch(void* const* d_in, const int* in_sizes, int n_in,
                              void* d_out, int out_size, void* d_ws, size_t ws_size,
                              hipStream_t stream) {
    const float* X  = (const float*)d_in[0];
    const float* W0 = (const float*)d_in[1];
    const float* b0 = (const float*)d_in[2];
    const float* W1 = (const float*)d_in[3];
    const float* b1 = (const float*)d_in[4];
    float* out = (float*)d_out;
    _Float16* wsw = (_Float16*)d_ws;  // needs 768 KB

    convert_w_kernel<<<(CVT_THREADS + 255) / 256, 256, 0, stream>>>(W0, W1, wsw);
    cin_kernel<<<BATCH / 2, 256, 0, stream>>>(X, b0, b1, wsw, out);
}

// Round 14
// 168.756 us; speedup vs baseline: 1.0189x; 1.0189x over previous
//
#include <hip/hip_runtime.h>

// CIN forward: B=2048, F=32, DIM=64, layers (128,128)
// out[b, 0:64]   = sum_d relu(W0 @ z0 + b0)[64:128, d]
// out[b, 64:192] = sum_d relu(W1 @ z1 + b1)[0:128, d]
// z0[h*32+m, d] = x[h,d]*x[m,d]   (h,m in [0,32))
// z1[h*32+m, d] = h1[h,d]*x[m,d]  (h in [0,64), m in [0,32)), h1 = layer0 rows 0..63
//
// R14: R13's 8-stream x 2-d L1 (0.5 pk_mul/MFMA — VALUBusy 38->24 confirmed)
// with the prefetch fixed: FULL-K-step lead (load all 8 streams of ks+1 at
// top of iter ks; consume ks's 8 held from last iter; unroll-2 ping-pong so
// renaming kills rotation movs). R13 stalled at 39% MfmaUtil because H-frags
// led consumption by only ~8 MFMAs (~40cy) vs ~200-300cy L2 latency.
// Register cost: 16 v8h live = ~84-96 arch VGPR + 64 acc -> 3 waves/SIMD via
// launch_bounds(256,3). R7(2w/SIMD,VGPR84) == R8(4w/SIMD,VGPR64) == 88.5us
// proved occupancy 2-4 w/SIMD is ~free on this kernel -> cheap trade.
// L0 unchanged (R5c 4-stream form). Epilogue pbuf cross-wave d-sum as R13.
//
// A-frag swizzle (16x16x32): wsw[ks*4096 + s*512 + lane*8 + j]
//   = W[(s*16 + (lane&15))*K + ks*32 + (lane>>4)*8 + j]

#define BATCH 2048
#define FSZ   32
#define DIM   64
#define K0    1024
#define K1    2048
#define OUTC  192

#define W0_ELEMS (128 * K0)            // 131072 f16
#define W1_ELEMS (128 * K1)            // 262144 f16
#define TOT_ELEMS (W0_ELEMS + W1_ELEMS)
#define CVT_THREADS (TOT_ELEMS / 4)    // 98304 -> 384 blocks

typedef _Float16 v8h __attribute__((ext_vector_type(8)));
typedef _Float16 v4h __attribute__((ext_vector_type(4)));
typedef _Float16 v2h __attribute__((ext_vector_type(2)));
typedef float    v4f __attribute__((ext_vector_type(4)));

#define XT_PITCH 40   // xT[d][m]: 80B rows, 16B-aligned v8h loads

// One thread per 4 output f16: coalesced 8B stores, aligned float4 reads.
__global__ void convert_w_kernel(const float* __restrict__ W0,
                                 const float* __restrict__ W1,
                                 _Float16* __restrict__ wsw) {
    int t = blockIdx.x * blockDim.x + threadIdx.x;
    if (t >= CVT_THREADS) return;
    int e = t * 4;
    const float* src;
    _Float16* dst;
    if (e < W0_ELEMS) {
        int j0 = e & 7, lane = (e >> 3) & 63, s = (e >> 9) & 7, ks = e >> 12;
        src = W0 + (size_t)(s * 16 + (lane & 15)) * K0
                 + ks * 32 + (lane >> 4) * 8 + j0;
        dst = wsw + e;
    } else {
        int u = e - W0_ELEMS;
        int j0 = u & 7, lane = (u >> 3) & 63, s = (u >> 9) & 7, ks = u >> 12;
        src = W1 + (size_t)(s * 16 + (lane & 15)) * K1
                 + ks * 32 + (lane >> 4) * 8 + j0;
        dst = wsw + W0_ELEMS + u;
    }
    float4 v = *(const float4*)src;
    dst[0] = (_Float16)v.x;
    dst[1] = (_Float16)v.y;
    dst[2] = (_Float16)v.z;
    dst[3] = (_Float16)v.w;
}

__device__ __forceinline__ v4f mfma16(v8h a, v8h b, v4f c) {
    return __builtin_amdgcn_mfma_f32_16x16x32_f16(a, b, c, 0, 0, 0);
}

__global__ __launch_bounds__(256, 3) void cin_kernel(
    const float* __restrict__ X,      // (B, 32, 64) fp32
    const float* __restrict__ b0,     // (128,)
    const float* __restrict__ b1,     // (128,)
    const _Float16* __restrict__ Wsw, // swizzled W0 then W1 (f16)
    float* __restrict__ out)          // (B, 192) fp32
{
    __shared__ _Float16 xT[2][DIM * XT_PITCH];   // xT[p][d][m]      (10240 B)
    __shared__ _Float16 xS[2][FSZ * 64];         // xS[p][m][c*4+t]  ( 8192 B)
    __shared__ _Float16 h1S[2][64 * 64];         // h1S[p][h][c*4+t] (16384 B)
    __shared__ float    pbuf[2][2][128];         // L1 d-sum partials ( 2048 B)

    const int b0i  = blockIdx.x * 2;
    const int tid  = threadIdx.x;
    const int wave = tid >> 6;
    const int lane = tid & 63;
    const int p    = wave & 1;        // batch member
    const int rh   = wave >> 1;       // L0: row half; L1: d half
    const int quad = lane >> 4;
    const int col  = lane & 15;

    // ---- stage both batches' x -> LDS (both layouts, f16) ----
    #pragma unroll
    for (int i = 0; i < 4; ++i) {
        int idx = tid + i * 256;               // float4 index 0..1023
        int pp = idx >> 9, r4 = idx & 511;
        float4 v = *(const float4*)(X + (size_t)(b0i + pp) * (FSZ * DIM) + r4 * 4);
        int m = (r4 * 4) >> 6, d = (r4 * 4) & 63;
        int tq = d >> 4, cc = d & 15;          // constant within the float4
        _Float16 f0 = (_Float16)v.x, f1 = (_Float16)v.y,
                 f2 = (_Float16)v.z, f3 = (_Float16)v.w;
        xT[pp][(d + 0) * XT_PITCH + m] = f0;
        xT[pp][(d + 1) * XT_PITCH + m] = f1;
        xT[pp][(d + 2) * XT_PITCH + m] = f2;
        xT[pp][(d + 3) * XT_PITCH + m] = f3;
        xS[pp][m * 64 + (cc + 0) * 4 + tq] = f0;
        xS[pp][m * 64 + (cc + 1) * 4 + tq] = f1;
        xS[pp][m * 64 + (cc + 2) * 4 + tq] = f2;
        xS[pp][m * 64 + (cc + 3) * 4 + tq] = f3;
    }
    __syncthreads();

    // K-invariant x parts of B fragments: xv8[t][j] = x[quad*8+j][16t+col]
    v8h xv8[4];
    #pragma unroll
    for (int t = 0; t < 4; ++t)
        xv8[t] = *(const v8h*)(&xT[p][(16 * t + col) * XT_PITCH + quad * 8]);

    const _Float16* Wb  = Wsw + (size_t)(rh * 4) * 512 + (size_t)lane * 8;
    const _Float16* xSp = &xS[p][col * 4];

    // ================= layer 0 (R5c form, unchanged) =================
    v4f acc[4][4];
    #pragma unroll
    for (int f = 0; f < 4; ++f)
        #pragma unroll
        for (int t = 0; t < 4; ++t) acc[f][t] = (v4f)0.0f;

    {
        v8h aC[4], aN[4];
        v4h svC, svN;
        #pragma unroll
        for (int i = 0; i < 4; ++i) aC[i] = *(const v8h*)(Wb + i * 512);
        svC = *(const v4h*)(xSp);
        #pragma unroll 2
        for (int ks = 0; ks < 32; ++ks) {
            const int kn = (ks + 1) & 31;      // clamped prefetch
            const _Float16* Wn = Wb + (size_t)kn * 4096;
            #pragma unroll
            for (int i = 0; i < 4; ++i) aN[i] = *(const v8h*)(Wn + i * 512);
            svN = *(const v4h*)(xSp + kn * 64);
            #pragma unroll
            for (int t = 0; t < 4; ++t) {
                _Float16 s = svC[t];
                v8h s8 = {s, s, s, s, s, s, s, s};
                v8h bfr = s8 * xv8[t];
                acc[0][t] = mfma16(aC[0], bfr, acc[0][t]);
                acc[1][t] = mfma16(aC[1], bfr, acc[1][t]);
                acc[2][t] = mfma16(aC[2], bfr, acc[2][t]);
                acc[3][t] = mfma16(aC[3], bfr, acc[3][t]);
            }
            #pragma unroll
            for (int i = 0; i < 4; ++i) aC[i] = aN[i];
            svC = svN;
        }
    }

    // ---- epilogue 0 ----
    // rh=0: rows 0..63 -> h1S[p] (packed v4h writes); rh=1: rows 64..127 -> out
    if (rh == 0) {
        #pragma unroll
        for (int f = 0; f < 4; ++f) {
            #pragma unroll
            for (int reg = 0; reg < 4; ++reg) {
                const int o = f * 16 + quad * 4 + reg;
                const float bias = b0[o];
                v4h pk;
                #pragma unroll
                for (int t = 0; t < 4; ++t) {
                    float v = acc[f][t][reg] + bias;
                    v = v > 0.0f ? v : 0.0f;
                    pk[t] = (_Float16)v;
                }
                *(v4h*)(&h1S[p][o * 64 + col * 4]) = pk;
            }
        }
    } else {
        #pragma unroll
        for (int f = 0; f < 4; ++f) {
            #pragma unroll
            for (int reg = 0; reg < 4; ++reg) {
                const int o = 64 + f * 16 + quad * 4 + reg;
                const float bias = b0[o];
                float s = 0.0f;
                #pragma unroll
                for (int t = 0; t < 4; ++t) {
                    float v = acc[f][t][reg] + bias;
                    s += (v > 0.0f ? v : 0.0f);
                }
                s += __shfl_xor(s, 1);
                s += __shfl_xor(s, 2);
                s += __shfl_xor(s, 4);
                s += __shfl_xor(s, 8);
                if (col == 0) out[(size_t)(b0i + p) * OUTC + (o - 64)] = s;
            }
        }
    }
    __syncthreads();   // h1S visible to all waves

    // ===== layer 1: 8 streams x 2 d-groups per wave, FULL K-step lead =====
    v8h xw0 = (rh == 0) ? xv8[0] : xv8[2];
    v8h xw1 = (rh == 0) ? xv8[1] : xv8[3];

    v4f a1[8][2];
    #pragma unroll
    for (int f = 0; f < 8; ++f) {
        a1[f][0] = (v4f)0.0f;
        a1[f][1] = (v4f)0.0f;
    }

    {
        const _Float16* Wb1 = Wsw + W0_ELEMS + (size_t)lane * 8;
        const _Float16* hSp = &h1S[p][col * 4 + rh * 2];
        v8h C[8], N[8];
        v2h svC, svN;
        #pragma unroll
        for (int i = 0; i < 8; ++i) C[i] = *(const v8h*)(Wb1 + i * 512);
        svC = *(const v2h*)(hSp);
        #pragma unroll 2
        for (int ks = 0; ks < 64; ++ks) {
            const int kn = (ks + 1) & 63;      // clamped prefetch (last unused)
            const _Float16* Wn = Wb1 + (size_t)kn * 4096;
            #pragma unroll
            for (int i = 0; i < 8; ++i) N[i] = *(const v8h*)(Wn + i * 512);
            svN = *(const v2h*)(hSp + kn * 64);
            _Float16 s0 = svC[0], s1 = svC[1];
            v8h s08 = {s0, s0, s0, s0, s0, s0, s0, s0};
            v8h s18 = {s1, s1, s1, s1, s1, s1, s1, s1};
            v8h bf0 = s08 * xw0;
            v8h bf1 = s18 * xw1;
            #pragma unroll
            for (int f = 0; f < 8; ++f) {
                a1[f][0] = mfma16(C[f], bf0, a1[f][0]);
                a1[f][1] = mfma16(C[f], bf1, a1[f][1]);
            }
            #pragma unroll
            for (int i = 0; i < 8; ++i) C[i] = N[i];
            svC = svN;
        }
    }

    // ---- epilogue 1: per-wave 32-d partials -> pbuf, combine across rh ----
    #pragma unroll
    for (int f = 0; f < 8; ++f) {
        #pragma unroll
        for (int reg = 0; reg < 4; ++reg) {
            const int o = f * 16 + quad * 4 + reg;
            const float bias = b1[o];
            float v0 = a1[f][0][reg] + bias; v0 = v0 > 0.0f ? v0 : 0.0f;
            float v1 = a1[f][1][reg] + bias; v1 = v1 > 0.0f ? v1 : 0.0f;
            float s = v0 + v1;
            s += __shfl_xor(s, 1);
            s += __shfl_xor(s, 2);
            s += __shfl_xor(s, 4);
            s += __shfl_xor(s, 8);
            if (col == 0) pbuf[p][rh][o] = s;
        }
    }
    __syncthreads();
    if (rh == 0) {
        float* op = out + (size_t)(b0i + p) * OUTC + 64;
        op[lane]      = pbuf[p][0][lane]      + pbuf[p][1][lane];
        op[64 + lane] = pbuf[p][0][64 + lane] + pbuf[p][1][64 + lane];
    }
}

extern "C" void kernel_launch(void* const* d_in, const int* in_sizes, int n_in,
                              void* d_out, int out_size, void* d_ws, size_t ws_size,
                              hipStream_t stream) {
    const float* X  = (const float*)d_in[0];
    const float* W0 = (const float*)d_in[1];
    const float* b0 = (const float*)d_in[2];
    const float* W1 = (const float*)d_in[3];
    const float* b1 = (const float*)d_in[4];
    float* out = (float*)d_out;
    _Float16* wsw = (_Float16*)d_ws;  // needs 768 KB

    convert_w_kernel<<<(CVT_THREADS + 255) / 256, 256, 0, stream>>>(W0, W1, wsw);
    cin_kernel<<<BATCH / 2, 256, 0, stream>>>(X, b0, b1, wsw, out);
}